// Round 7
// baseline (390.500 us; speedup 1.0000x reference)
//
#include <hip/hip_runtime.h>

#define N_NODES 50000
#define N_EDGES 1600000
#define D_IN 128
#define D_HID 256

#define SCAN_BLOCK 256
#define SCAN_ELEMS 2048
#define SCAN_GRID ((N_NODES + SCAN_ELEMS - 1) / SCAN_ELEMS)   // 25

#define NBKT 196          // buckets = dst >> 8
#define BCAP 12288        // per-bucket capacity (mean 8163, +45 sigma)
#define CHUNK 1024        // edges per bin-kernel block (4/thread, registers)

typedef short bh8 __attribute__((ext_vector_type(8)));   // 8 bf16 (4 VGPRs)
typedef float f32x4 __attribute__((ext_vector_type(4))); // MFMA C/D

// ---------------------------------------------------------------------------
__device__ inline unsigned int f2_to_bf16x2(float a, float b) {
    unsigned int ua = __float_as_uint(a);
    ua = (ua + 0x7FFFu + ((ua >> 16) & 1u)) >> 16;
    unsigned int ub = __float_as_uint(b);
    ub = (ub + 0x7FFFu + ((ub >> 16) & 1u)) >> 16;
    return ua | (ub << 16);
}
__device__ inline unsigned short f_to_bf16(float a) {
    unsigned int ua = __float_as_uint(a);
    return (unsigned short)((ua + 0x7FFFu + ((ua >> 16) & 1u)) >> 16);
}
__device__ inline float2 bf16x2_to_f2(unsigned int p) {
    float2 r;
    r.x = __uint_as_float(p << 16);
    r.y = __uint_as_float(p & 0xFFFF0000u);
    return r;
}

// ---------------------------------------------------------------------------
// Phase A: fused degree histogram + coarse binning by dst>>8.
// 4 edges/thread staged in REGISTERS (LDS only for the 196-counter hist) ->
// 1563 blocks, high occupancy for the atomic streams.
__global__ __launch_bounds__(256) void bin_kernel(
        const int* __restrict__ src, const int* __restrict__ dst,
        int* __restrict__ deg, int* __restrict__ bcur,
        unsigned int* __restrict__ binned, int E) {
    __shared__ int hist[NBKT], base[NBKT];
    const int tid = threadIdx.x;
    if (tid < NBKT) hist[tid] = 0;
    __syncthreads();
    const int cbase = blockIdx.x * CHUNK;
    unsigned rec[4];
    int nv = 0;
    #pragma unroll
    for (int k = 0; k < 4; ++k) {
        int i = cbase + k * 256 + tid;            // coalesced
        if (i < E) {
            int s = src[i], d = dst[i];
            rec[k] = ((unsigned)s << 16) | (unsigned)d;   // d < 50000 < 2^16
            atomicAdd(&deg[d], 1);
            atomicAdd(&hist[d >> 8], 1);
            nv = k + 1;
        }
    }
    __syncthreads();
    if (tid < NBKT) {
        int h = hist[tid];
        base[tid] = h ? atomicAdd(&bcur[tid], h) : 0;
        hist[tid] = 0;                            // reuse as local cursor
    }
    __syncthreads();
    #pragma unroll
    for (int k = 0; k < 4; ++k) {
        if (k < nv) {
            unsigned r = rec[k];
            int d = r & 0xFFFF;
            int b = d >> 8;
            int p = base[b] + atomicAdd(&hist[b], 1);
            binned[(size_t)b * BCAP + p] = (r & 0xFFFF0000u) | (unsigned)(d & 0xFF);
        }
    }
}

// ---------------------------------------------------------------------------
// scan1: block-local exclusive scan of deg -> rowptr; also writes dinv.
__global__ __launch_bounds__(SCAN_BLOCK) void scan1(const int* __restrict__ deg,
                                                    int* __restrict__ rowptr,
                                                    float* __restrict__ dinv,
                                                    int* __restrict__ blocksums,
                                                    int n) {
    __shared__ int sm[SCAN_BLOCK];
    int base = blockIdx.x * SCAN_ELEMS + threadIdx.x * 8;
    int v[8];
    int tsum = 0;
    #pragma unroll
    for (int k = 0; k < 8; ++k) {
        int idx = base + k;
        v[k] = (idx < n) ? deg[idx] : 0;
        if (idx < n) dinv[idx] = rsqrtf((float)(v[k] + 1));
        tsum += v[k];
    }
    sm[threadIdx.x] = tsum;
    __syncthreads();
    for (int off = 1; off < SCAN_BLOCK; off <<= 1) {
        int add = (threadIdx.x >= off) ? sm[threadIdx.x - off] : 0;
        __syncthreads();
        sm[threadIdx.x] += add;
        __syncthreads();
    }
    int ex = sm[threadIdx.x] - tsum;
    #pragma unroll
    for (int k = 0; k < 8; ++k) {
        int idx = base + k;
        if (idx < n) rowptr[idx] = ex;
        ex += v[k];
    }
    if (threadIdx.x == SCAN_BLOCK - 1) blocksums[blockIdx.x] = sm[threadIdx.x];
}

__global__ void scan2(int* __restrict__ blocksums, int g) {
    if (threadIdx.x == 0 && blockIdx.x == 0) {
        int run = 0;
        for (int i = 0; i < g; ++i) { int t = blocksums[i]; blocksums[i] = run; run += t; }
    }
}

__global__ __launch_bounds__(SCAN_BLOCK) void scan3(int* __restrict__ rowptr,
                                                    const int* __restrict__ blocksums,
                                                    int n) {
    int base = blockIdx.x * SCAN_ELEMS + threadIdx.x * 8;
    int boff = blocksums[blockIdx.x];
    #pragma unroll
    for (int k = 0; k < 8; ++k) {
        int idx = base + k;
        if (idx < n) rowptr[idx] += boff;
    }
}

// ---------------------------------------------------------------------------
// Phase B: within-bucket placement. src u16 staged in LDS then burst-copied;
// weight eW = dinv[s]*dinv[d] written directly (bucket window is L2-local).
__global__ __launch_bounds__(256) void place_kernel(
        const unsigned int* __restrict__ binned, const int* __restrict__ bcur,
        const int* __restrict__ rowptr, const float* __restrict__ dinv,
        unsigned short* __restrict__ eS, float* __restrict__ eW, int nNodes) {
    __shared__ int cur[256];
    __shared__ float sdinv[256];
    __shared__ unsigned short recS[BCAP];
    const int b = blockIdx.x, tid = threadIdx.x;
    const int nbase = b * 256;
    const int regionBase = rowptr[nbase];        // nbase <= 49920 < nNodes
    int node = nbase + tid;
    cur[tid] = (node < nNodes) ? (rowptr[node] - regionBase) : 0;
    sdinv[tid] = (node < nNodes) ? dinv[node] : 0.0f;
    __syncthreads();
    int cnt = bcur[b];
    if (cnt <= BCAP) {
        for (int j = tid; j < cnt; j += 256) {
            unsigned r = binned[(size_t)b * BCAP + j];
            int dl = r & 0xFF;
            int s = r >> 16;
            int p = atomicAdd(&cur[dl], 1);
            recS[p] = (unsigned short)s;
            eW[regionBase + p] = dinv[s] * sdinv[dl];
        }
        __syncthreads();
        for (int j = tid; j < cnt; j += 256)
            eS[regionBase + j] = recS[j];
    } else {                                     // never taken (45-sigma guard)
        for (int j = tid; j < cnt; j += 256) {
            unsigned r = binned[(size_t)b * BCAP + j];
            int dl = r & 0xFF;
            int s = r >> 16;
            int p = atomicAdd(&cur[dl], 1);
            eS[regionBase + p] = (unsigned short)s;
            eW[regionBase + p] = dinv[s] * sdinv[dl];
        }
    }
}

// ---------------------------------------------------------------------------
// f32 -> packed bf16x2 (4 floats / thread)
__global__ __launch_bounds__(256) void cvt_bf16(const float4* __restrict__ in,
                                                uint2* __restrict__ out, int n4) {
    int i = blockIdx.x * blockDim.x + threadIdx.x;
    if (i < n4) {
        float4 v = in[i];
        out[i] = make_uint2(f2_to_bf16x2(v.x, v.y), f2_to_bf16x2(v.z, v.w));
    }
}

// Both weights: W[k][n] fp32 -> WT[n][k] bf16
__global__ __launch_bounds__(256) void cvtT_both(const float* __restrict__ W1,
                                                 const float* __restrict__ W2,
                                                 unsigned short* __restrict__ W1T,
                                                 unsigned short* __restrict__ W2T) {
    int t = blockIdx.x * blockDim.x + threadIdx.x;
    const int SZ = D_IN * D_HID;
    if (t < SZ) {
        int n = t / D_IN, k = t - n * D_IN;       // W1T[n][k], K=128, N=256
        W1T[t] = f_to_bf16(W1[(size_t)k * D_HID + n]);
    } else if (t < 2 * SZ) {
        int u = t - SZ;
        int n = u / D_HID, k = u - n * D_HID;     // W2T[n][k], K=256, N=128
        W2T[u] = f_to_bf16(W2[(size_t)k * D_IN + n]);
    }
}

// ---------------------------------------------------------------------------
// Gather aggregation, bf16 rows, fp32 accumulate. One 64-lane wave per node.
// Edge = (eS u16, eW f32) coalesced; weights broadcast by shfl.
template<bool OUT_BF16>
__global__ __launch_bounds__(256) void gather_agg_bf16(
        const unsigned int* __restrict__ hb,   // [N, 64] packed bf16x2
        const unsigned short* __restrict__ eS,
        const float* __restrict__ eW,
        const int* __restrict__ rowptr, const int* __restrict__ deg,
        const float* __restrict__ dinv, const float* __restrict__ bias,
        void* __restrict__ out, int n) {
    int lane = threadIdx.x & 63;
    int node = blockIdx.x * 4 + (threadIdx.x >> 6);
    if (node >= n) return;
    int start = rowptr[node];
    int cnt = deg[node];
    float dn = dinv[node];
    float2 hv = bf16x2_to_f2(hb[(size_t)node * 64 + lane]);
    float2 acc = make_float2(dn * dn * hv.x, dn * dn * hv.y);
    for (int c0 = 0; c0 < cnt; c0 += 64) {
        int m = min(64, cnt - c0);
        int   es = (lane < m) ? (int)eS[start + c0 + lane] : 0;
        float ws = (lane < m) ? eW[start + c0 + lane] : 0.0f;  // 0 kills OOB
        int mr = (m + 7) & ~7;
        for (int j = 0; j < mr; j += 8) {
            float2 vv[8];
            float ww[8];
            #pragma unroll
            for (int k = 0; k < 8; ++k) {
                int sj = __shfl(es, j + k);
                ww[k] = __shfl(ws, j + k);
                vv[k] = bf16x2_to_f2(hb[(size_t)sj * 64 + lane]);
            }
            #pragma unroll
            for (int k = 0; k < 8; ++k) {
                acc.x += ww[k] * vv[k].x;
                acc.y += ww[k] * vv[k].y;
            }
        }
    }
    if (OUT_BF16) {
        ((unsigned int*)out)[(size_t)node * 64 + lane] = f2_to_bf16x2(acc.x, acc.y);
    } else {
        float2 b = ((const float2*)bias)[lane];
        acc.x += b.x;
        acc.y += b.y;
        ((float2*)((float*)out + (size_t)node * D_IN))[lane] = acc;
    }
}

// ---------------------------------------------------------------------------
// MFMA bf16 GEMM: C[M,N] = A[M,K] @ W[K,N]. MODE 1: fused bias+ReLU; 2: plain.
template<int N, int K, int MODE>
__global__ __launch_bounds__(256) void gemm_mfma(
        const unsigned short* __restrict__ WT,  // [N][K] bf16
        const unsigned int* __restrict__ Ab,    // [M][K/2] packed bf16
        const float* __restrict__ bias,
        unsigned short* __restrict__ Cb,        // [M][N] bf16
        int M) {
    constexpr int KP = K + 8;
    constexpr int KSTEPS = K / 32;
    constexpr int TPW = N / 64;
    __shared__ unsigned short Bs[N * KP];

    const int tid = threadIdx.x;
    for (int c = tid; c < N * (K / 8); c += 256) {
        int nn = c / (K / 8), kc = c - nn * (K / 8);
        uint4 v = ((const uint4*)(WT + (size_t)nn * K))[kc];
        *(uint4*)&Bs[nn * KP + kc * 8] = v;
    }
    __syncthreads();

    const int wave = tid >> 6, lane = tid & 63;
    const int n0 = wave * (TPW * 16);
    const int m_base = blockIdx.x * 128;
    const int rit = lane & 15;
    const int kg = lane >> 4;

    f32x4 acc[8][TPW];
    #pragma unroll
    for (int rg = 0; rg < 8; ++rg)
        #pragma unroll
        for (int t = 0; t < TPW; ++t)
            acc[rg][t] = (f32x4){0.f, 0.f, 0.f, 0.f};

    bh8 a0[8], a1[8];
    #define LOAD_A(KS, DST)                                                  \
        _Pragma("unroll")                                                    \
        for (int rg = 0; rg < 8; ++rg) {                                     \
            int m = m_base + rg * 16 + rit;                                  \
            m = min(m, M - 1);                                               \
            DST[rg] = *(const bh8*)(Ab + (size_t)m * (K / 2) + (KS)*16 + kg * 4); \
        }

    LOAD_A(0, a0)
    #pragma unroll
    for (int ks = 0; ks < KSTEPS; ++ks) {
        if (ks + 1 < KSTEPS) {
            if ((ks & 1) == 0) { LOAD_A(ks + 1, a1) }
            else               { LOAD_A(ks + 1, a0) }
        }
        #pragma unroll
        for (int t = 0; t < TPW; ++t) {
            bh8 b = *(const bh8*)&Bs[(n0 + t * 16 + rit) * KP + ks * 32 + kg * 8];
            #pragma unroll
            for (int rg = 0; rg < 8; ++rg) {
                bh8 a = ((ks & 1) == 0) ? a0[rg] : a1[rg];
                acc[rg][t] = __builtin_amdgcn_mfma_f32_16x16x32_bf16(
                    a, b, acc[rg][t], 0, 0, 0);
            }
        }
    }
    #undef LOAD_A

    #pragma unroll
    for (int t = 0; t < TPW; ++t) {
        int col = n0 + t * 16 + rit;
        float bv = (MODE == 1) ? bias[col] : 0.0f;
        #pragma unroll
        for (int rg = 0; rg < 8; ++rg) {
            #pragma unroll
            for (int i = 0; i < 4; ++i) {
                int m = m_base + rg * 16 + kg * 4 + i;
                float v = acc[rg][t][i];
                if (MODE == 1) { v += bv; v = fmaxf(v, 0.0f); }
                if (m < M) Cb[(size_t)m * N + col] = f_to_bf16(v);
            }
        }
    }
}

// ---------------------------------------------------------------------------
extern "C" void kernel_launch(void* const* d_in, const int* in_sizes, int n_in,
                              void* d_out, int out_size, void* d_ws, size_t ws_size,
                              hipStream_t stream) {
    const float* x  = (const float*)d_in[0];
    const int*   ei = (const int*)d_in[1];          // [2, E] int32
    const float* W1 = (const float*)d_in[2];
    const float* b1 = (const float*)d_in[3];
    const float* W2 = (const float*)d_in[4];
    const float* b2 = (const float*)d_in[5];
    const int* src = ei;
    const int* dst = ei + N_EDGES;
    float* out = (float*)d_out;

    char* ws = (char*)d_ws;
    size_t off = 0;
    auto carve = [&](size_t bytes) {
        char* p = ws + off;
        off += (bytes + 255) & ~size_t(255);
        return p;
    };
    // deg and bcur adjacent -> single memset
    int*   deg       = (int*)  carve((N_NODES + 256) * sizeof(int));
    int*   bcur      = deg + N_NODES;
    int*   rowptr    = (int*)  carve(N_NODES * sizeof(int));
    int*   blocksums = (int*)  carve(SCAN_GRID * sizeof(int));
    float* dinv      = (float*)carve(N_NODES * sizeof(float));
    unsigned int*   binned = (unsigned int*)  carve((size_t)NBKT * BCAP * sizeof(unsigned int));
    unsigned short* eS     = (unsigned short*)carve((size_t)N_EDGES * sizeof(unsigned short));
    float*          eWt    = (float*)         carve((size_t)N_EDGES * sizeof(float));
    unsigned int* xb   = (unsigned int*)carve((size_t)N_NODES * 64 * sizeof(unsigned int));
    unsigned int* aggb = (unsigned int*)carve((size_t)N_NODES * 64 * sizeof(unsigned int));
    unsigned int* h1b  = (unsigned int*)carve((size_t)N_NODES * 128 * sizeof(unsigned int));
    unsigned short* W1T = (unsigned short*)carve((size_t)D_IN * D_HID * sizeof(unsigned short));
    unsigned short* W2T = (unsigned short*)carve((size_t)D_HID * D_IN * sizeof(unsigned short));
    unsigned int* t2b = xb;   // reuse: xb dead after gather1
    (void)ws_size;

    // 1. CSR build: bin (fused deg) -> scan (fused dinv) -> place (fused eW)
    hipMemsetAsync(deg, 0, (N_NODES + 256) * sizeof(int), stream);
    bin_kernel<<<(N_EDGES + CHUNK - 1) / CHUNK, 256, 0, stream>>>(
        src, dst, deg, bcur, binned, N_EDGES);
    scan1<<<SCAN_GRID, SCAN_BLOCK, 0, stream>>>(deg, rowptr, dinv, blocksums, N_NODES);
    scan2<<<1, 64, 0, stream>>>(blocksums, SCAN_GRID);
    scan3<<<SCAN_GRID, SCAN_BLOCK, 0, stream>>>(rowptr, blocksums, N_NODES);
    place_kernel<<<NBKT, 256, 0, stream>>>(binned, bcur, rowptr, dinv,
                                           eS, eWt, N_NODES);

    // 2. conversions
    cvt_bf16<<<(N_NODES * D_IN / 4 + 255) / 256, 256, 0, stream>>>(
        (const float4*)x, (uint2*)xb, N_NODES * D_IN / 4);
    cvtT_both<<<(2 * D_IN * D_HID + 255) / 256, 256, 0, stream>>>(W1, W2, W1T, W2T);

    // 3. aggb = bf16(S @ x)
    gather_agg_bf16<true><<<(N_NODES + 3) / 4, 256, 0, stream>>>(
        xb, eS, eWt, rowptr, deg, dinv, nullptr, (void*)aggb, N_NODES);

    // 4. h1b = bf16(relu(aggb @ W1 + b1))   [MFMA]
    gemm_mfma<D_HID, D_IN, 1><<<(N_NODES + 127) / 128, 256, 0, stream>>>(
        W1T, aggb, b1, (unsigned short*)h1b, N_NODES);

    // 5. t2b = bf16(h1b @ W2)               [MFMA]
    gemm_mfma<D_IN, D_HID, 2><<<(N_NODES + 127) / 128, 256, 0, stream>>>(
        W2T, h1b, nullptr, (unsigned short*)t2b, N_NODES);

    // 6. out = S @ t2 + b2
    gather_agg_bf16<false><<<(N_NODES + 3) / 4, 256, 0, stream>>>(
        t2b, eS, eWt, rowptr, deg, dinv, b2, (void*)out, N_NODES);
}

// Round 8
// 311.555 us; speedup vs baseline: 1.2534x; 1.2534x over previous
//
#include <hip/hip_runtime.h>

#define N_NODES 50000
#define N_EDGES 1600000
#define D_IN 128
#define D_HID 256

#define NBKT 196          // buckets = dst >> 8
#define BCAP 12288        // per-bucket capacity (mean 8163, +45 sigma)
#define CHUNK 4096        // edges per bin-kernel block

typedef short bh8 __attribute__((ext_vector_type(8)));   // 8 bf16 (4 VGPRs)
typedef float f32x4 __attribute__((ext_vector_type(4))); // MFMA C/D

// ---------------------------------------------------------------------------
__device__ inline unsigned int f2_to_bf16x2(float a, float b) {
    unsigned int ua = __float_as_uint(a);
    ua = (ua + 0x7FFFu + ((ua >> 16) & 1u)) >> 16;
    unsigned int ub = __float_as_uint(b);
    ub = (ub + 0x7FFFu + ((ub >> 16) & 1u)) >> 16;
    return ua | (ub << 16);
}
__device__ inline unsigned short f_to_bf16(float a) {
    unsigned int ua = __float_as_uint(a);
    return (unsigned short)((ua + 0x7FFFu + ((ua >> 16) & 1u)) >> 16);
}
__device__ inline float2 bf16x2_to_f2(unsigned int p) {
    float2 r;
    r.x = __uint_as_float(p << 16);
    r.y = __uint_as_float(p & 0xFFFF0000u);
    return r;
}

// ---------------------------------------------------------------------------
// Phase A: coarse binning by dst>>8 with IN-LDS bucket sort so the global
// bucket-segment writes are contiguous (full-line merging). No deg atomics.
__global__ __launch_bounds__(256) void bin_kernel(
        const int* __restrict__ src, const int* __restrict__ dst,
        int* __restrict__ bcur, unsigned int* __restrict__ binned, int E) {
    __shared__ unsigned int staged[CHUNK];   // 16 KB
    __shared__ unsigned int sorted[CHUNK];   // 16 KB
    __shared__ int hist[NBKT], lbase[NBKT], gbase[NBKT];
    __shared__ int sc[256];
    const int tid = threadIdx.x;
    if (tid < NBKT) hist[tid] = 0;
    __syncthreads();
    const int cbase = blockIdx.x * CHUNK;
    const int n = min(CHUNK, E - cbase);
    for (int i = tid; i < n; i += 256) {
        int s = src[cbase + i], d = dst[cbase + i];
        staged[i] = ((unsigned)s << 16) | (unsigned)d;   // d < 50000 < 2^16
        atomicAdd(&hist[d >> 8], 1);
    }
    __syncthreads();
    // exclusive scan of hist[196] + one global reservation per bucket
    int h = (tid < NBKT) ? hist[tid] : 0;
    sc[tid] = h;
    __syncthreads();
    for (int off = 1; off < 256; off <<= 1) {
        int a = (tid >= off) ? sc[tid - off] : 0;
        __syncthreads();
        sc[tid] += a;
        __syncthreads();
    }
    if (tid < NBKT) {
        lbase[tid] = sc[tid] - h;
        gbase[tid] = h ? atomicAdd(&bcur[tid], h) : 0;
        hist[tid] = 0;                                   // reuse as cursor
    }
    __syncthreads();
    // permute into bucket order in LDS
    for (int i = tid; i < n; i += 256) {
        unsigned r = staged[i];
        int b = (r & 0xFFFF) >> 8;
        sorted[lbase[b] + atomicAdd(&hist[b], 1)] = r;
    }
    __syncthreads();
    // contiguous segment write-out: consecutive j -> consecutive addresses
    for (int j = tid; j < n; j += 256) {
        unsigned r = sorted[j];
        int b = (r & 0xFFFF) >> 8;
        binned[(size_t)b * BCAP + gbase[b] + (j - lbase[b])] = r;
    }
}

// ---------------------------------------------------------------------------
// Exclusive scan of the 196 bucket counts -> bucket region bases.
__global__ __launch_bounds__(256) void scanB(const int* __restrict__ bcur,
                                             int* __restrict__ brow) {
    __shared__ int sc[256];
    const int tid = threadIdx.x;
    int v = (tid < NBKT) ? bcur[tid] : 0;
    sc[tid] = v;
    __syncthreads();
    for (int off = 1; off < 256; off <<= 1) {
        int a = (tid >= off) ? sc[tid - off] : 0;
        __syncthreads();
        sc[tid] += a;
        __syncthreads();
    }
    if (tid < NBKT) brow[tid] = sc[tid] - v;
}

// ---------------------------------------------------------------------------
// Per-bucket node histogram -> deg, dinv, rowptr (replaces global deg atomics
// and the 50000-wide scan kernels).
__global__ __launch_bounds__(256) void count_kernel(
        const unsigned int* __restrict__ binned, const int* __restrict__ bcur,
        const int* __restrict__ brow, int* __restrict__ deg,
        float* __restrict__ dinv, int* __restrict__ rowptr, int nNodes) {
    __shared__ int h[256], sc[256];
    const int b = blockIdx.x, tid = threadIdx.x;
    h[tid] = 0;
    __syncthreads();
    const int cnt = bcur[b];
    for (int j = tid; j < cnt; j += 256)
        atomicAdd(&h[binned[(size_t)b * BCAP + j] & 0xFF], 1);
    __syncthreads();
    int d0 = h[tid];
    sc[tid] = d0;
    __syncthreads();
    for (int off = 1; off < 256; off <<= 1) {
        int a = (tid >= off) ? sc[tid - off] : 0;
        __syncthreads();
        sc[tid] += a;
        __syncthreads();
    }
    int node = b * 256 + tid;
    if (node < nNodes) {
        deg[node] = d0;
        dinv[node] = rsqrtf((float)(d0 + 1));
        rowptr[node] = brow[b] + sc[tid] - d0;
    }
}

// ---------------------------------------------------------------------------
// Phase B: within-bucket placement. src u16 staged in LDS then burst-copied;
// weight eW = dinv[s]*dinv[d] written directly (bucket window is L2-local).
__global__ __launch_bounds__(256) void place_kernel(
        const unsigned int* __restrict__ binned, const int* __restrict__ bcur,
        const int* __restrict__ rowptr, const float* __restrict__ dinv,
        unsigned short* __restrict__ eS, float* __restrict__ eW, int nNodes) {
    __shared__ int cur[256];
    __shared__ float sdinv[256];
    __shared__ unsigned short recS[BCAP];
    const int b = blockIdx.x, tid = threadIdx.x;
    const int nbase = b * 256;
    const int regionBase = rowptr[nbase];        // nbase <= 49920 < nNodes
    int node = nbase + tid;
    cur[tid] = (node < nNodes) ? (rowptr[node] - regionBase) : 0;
    sdinv[tid] = (node < nNodes) ? dinv[node] : 0.0f;
    __syncthreads();
    int cnt = bcur[b];
    if (cnt <= BCAP) {
        for (int j = tid; j < cnt; j += 256) {
            unsigned r = binned[(size_t)b * BCAP + j];
            int dl = r & 0xFF;
            int s = r >> 16;
            int p = atomicAdd(&cur[dl], 1);
            recS[p] = (unsigned short)s;
            eW[regionBase + p] = dinv[s] * sdinv[dl];
        }
        __syncthreads();
        for (int j = tid; j < cnt; j += 256)
            eS[regionBase + j] = recS[j];
    } else {                                     // never taken (45-sigma guard)
        for (int j = tid; j < cnt; j += 256) {
            unsigned r = binned[(size_t)b * BCAP + j];
            int dl = r & 0xFF;
            int s = r >> 16;
            int p = atomicAdd(&cur[dl], 1);
            eS[regionBase + p] = (unsigned short)s;
            eW[regionBase + p] = dinv[s] * sdinv[dl];
        }
    }
}

// ---------------------------------------------------------------------------
// f32 -> packed bf16x2 (4 floats / thread)
__global__ __launch_bounds__(256) void cvt_bf16(const float4* __restrict__ in,
                                                uint2* __restrict__ out, int n4) {
    int i = blockIdx.x * blockDim.x + threadIdx.x;
    if (i < n4) {
        float4 v = in[i];
        out[i] = make_uint2(f2_to_bf16x2(v.x, v.y), f2_to_bf16x2(v.z, v.w));
    }
}

// Both weights: W[k][n] fp32 -> WT[n][k] bf16
__global__ __launch_bounds__(256) void cvtT_both(const float* __restrict__ W1,
                                                 const float* __restrict__ W2,
                                                 unsigned short* __restrict__ W1T,
                                                 unsigned short* __restrict__ W2T) {
    int t = blockIdx.x * blockDim.x + threadIdx.x;
    const int SZ = D_IN * D_HID;
    if (t < SZ) {
        int n = t / D_IN, k = t - n * D_IN;       // W1T[n][k], K=128, N=256
        W1T[t] = f_to_bf16(W1[(size_t)k * D_HID + n]);
    } else if (t < 2 * SZ) {
        int u = t - SZ;
        int n = u / D_HID, k = u - n * D_HID;     // W2T[n][k], K=256, N=128
        W2T[u] = f_to_bf16(W2[(size_t)k * D_IN + n]);
    }
}

// ---------------------------------------------------------------------------
// Gather aggregation, bf16 rows, fp32 accumulate. One 64-lane wave per node.
// Edge = (eS u16, eW f32) coalesced; weights broadcast by shfl.
template<bool OUT_BF16>
__global__ __launch_bounds__(256) void gather_agg_bf16(
        const unsigned int* __restrict__ hb,   // [N, 64] packed bf16x2
        const unsigned short* __restrict__ eS,
        const float* __restrict__ eW,
        const int* __restrict__ rowptr, const int* __restrict__ deg,
        const float* __restrict__ dinv, const float* __restrict__ bias,
        void* __restrict__ out, int n) {
    int lane = threadIdx.x & 63;
    int node = blockIdx.x * 4 + (threadIdx.x >> 6);
    if (node >= n) return;
    int start = rowptr[node];
    int cnt = deg[node];
    float dn = dinv[node];
    float2 hv = bf16x2_to_f2(hb[(size_t)node * 64 + lane]);
    float2 acc = make_float2(dn * dn * hv.x, dn * dn * hv.y);
    for (int c0 = 0; c0 < cnt; c0 += 64) {
        int m = min(64, cnt - c0);
        int   es = (lane < m) ? (int)eS[start + c0 + lane] : 0;
        float ws = (lane < m) ? eW[start + c0 + lane] : 0.0f;  // 0 kills OOB
        int mr = (m + 7) & ~7;
        for (int j = 0; j < mr; j += 8) {
            float2 vv[8];
            float ww[8];
            #pragma unroll
            for (int k = 0; k < 8; ++k) {
                int sj = __shfl(es, j + k);
                ww[k] = __shfl(ws, j + k);
                vv[k] = bf16x2_to_f2(hb[(size_t)sj * 64 + lane]);
            }
            #pragma unroll
            for (int k = 0; k < 8; ++k) {
                acc.x += ww[k] * vv[k].x;
                acc.y += ww[k] * vv[k].y;
            }
        }
    }
    if (OUT_BF16) {
        ((unsigned int*)out)[(size_t)node * 64 + lane] = f2_to_bf16x2(acc.x, acc.y);
    } else {
        float2 b = ((const float2*)bias)[lane];
        acc.x += b.x;
        acc.y += b.y;
        ((float2*)((float*)out + (size_t)node * D_IN))[lane] = acc;
    }
}

// ---------------------------------------------------------------------------
// MFMA bf16 GEMM: C[M,N] = A[M,K] @ W[K,N]. MODE 1: fused bias+ReLU; 2: plain.
template<int N, int K, int MODE>
__global__ __launch_bounds__(256) void gemm_mfma(
        const unsigned short* __restrict__ WT,  // [N][K] bf16
        const unsigned int* __restrict__ Ab,    // [M][K/2] packed bf16
        const float* __restrict__ bias,
        unsigned short* __restrict__ Cb,        // [M][N] bf16
        int M) {
    constexpr int KP = K + 8;
    constexpr int KSTEPS = K / 32;
    constexpr int TPW = N / 64;
    __shared__ unsigned short Bs[N * KP];

    const int tid = threadIdx.x;
    for (int c = tid; c < N * (K / 8); c += 256) {
        int nn = c / (K / 8), kc = c - nn * (K / 8);
        uint4 v = ((const uint4*)(WT + (size_t)nn * K))[kc];
        *(uint4*)&Bs[nn * KP + kc * 8] = v;
    }
    __syncthreads();

    const int wave = tid >> 6, lane = tid & 63;
    const int n0 = wave * (TPW * 16);
    const int m_base = blockIdx.x * 128;
    const int rit = lane & 15;
    const int kg = lane >> 4;

    f32x4 acc[8][TPW];
    #pragma unroll
    for (int rg = 0; rg < 8; ++rg)
        #pragma unroll
        for (int t = 0; t < TPW; ++t)
            acc[rg][t] = (f32x4){0.f, 0.f, 0.f, 0.f};

    bh8 a0[8], a1[8];
    #define LOAD_A(KS, DST)                                                  \
        _Pragma("unroll")                                                    \
        for (int rg = 0; rg < 8; ++rg) {                                     \
            int m = m_base + rg * 16 + rit;                                  \
            m = min(m, M - 1);                                               \
            DST[rg] = *(const bh8*)(Ab + (size_t)m * (K / 2) + (KS)*16 + kg * 4); \
        }

    LOAD_A(0, a0)
    #pragma unroll
    for (int ks = 0; ks < KSTEPS; ++ks) {
        if (ks + 1 < KSTEPS) {
            if ((ks & 1) == 0) { LOAD_A(ks + 1, a1) }
            else               { LOAD_A(ks + 1, a0) }
        }
        #pragma unroll
        for (int t = 0; t < TPW; ++t) {
            bh8 b = *(const bh8*)&Bs[(n0 + t * 16 + rit) * KP + ks * 32 + kg * 8];
            #pragma unroll
            for (int rg = 0; rg < 8; ++rg) {
                bh8 a = ((ks & 1) == 0) ? a0[rg] : a1[rg];
                acc[rg][t] = __builtin_amdgcn_mfma_f32_16x16x32_bf16(
                    a, b, acc[rg][t], 0, 0, 0);
            }
        }
    }
    #undef LOAD_A

    #pragma unroll
    for (int t = 0; t < TPW; ++t) {
        int col = n0 + t * 16 + rit;
        float bv = (MODE == 1) ? bias[col] : 0.0f;
        #pragma unroll
        for (int rg = 0; rg < 8; ++rg) {
            #pragma unroll
            for (int i = 0; i < 4; ++i) {
                int m = m_base + rg * 16 + kg * 4 + i;
                float v = acc[rg][t][i];
                if (MODE == 1) { v += bv; v = fmaxf(v, 0.0f); }
                if (m < M) Cb[(size_t)m * N + col] = f_to_bf16(v);
            }
        }
    }
}

// ---------------------------------------------------------------------------
extern "C" void kernel_launch(void* const* d_in, const int* in_sizes, int n_in,
                              void* d_out, int out_size, void* d_ws, size_t ws_size,
                              hipStream_t stream) {
    const float* x  = (const float*)d_in[0];
    const int*   ei = (const int*)d_in[1];          // [2, E] int32
    const float* W1 = (const float*)d_in[2];
    const float* b1 = (const float*)d_in[3];
    const float* W2 = (const float*)d_in[4];
    const float* b2 = (const float*)d_in[5];
    const int* src = ei;
    const int* dst = ei + N_EDGES;
    float* out = (float*)d_out;

    char* ws = (char*)d_ws;
    size_t off = 0;
    auto carve = [&](size_t bytes) {
        char* p = ws + off;
        off += (bytes + 255) & ~size_t(255);
        return p;
    };
    int*   bcur      = (int*)  carve(256 * sizeof(int));
    int*   brow      = (int*)  carve(256 * sizeof(int));
    int*   deg       = (int*)  carve(N_NODES * sizeof(int));
    int*   rowptr    = (int*)  carve(N_NODES * sizeof(int));
    float* dinv      = (float*)carve(N_NODES * sizeof(float));
    unsigned int*   binned = (unsigned int*)  carve((size_t)NBKT * BCAP * sizeof(unsigned int));
    unsigned short* eS     = (unsigned short*)carve((size_t)N_EDGES * sizeof(unsigned short));
    float*          eWt    = (float*)         carve((size_t)N_EDGES * sizeof(float));
    unsigned int* xb   = (unsigned int*)carve((size_t)N_NODES * 64 * sizeof(unsigned int));
    unsigned int* aggb = (unsigned int*)carve((size_t)N_NODES * 64 * sizeof(unsigned int));
    unsigned int* h1b  = (unsigned int*)carve((size_t)N_NODES * 128 * sizeof(unsigned int));
    unsigned short* W1T = (unsigned short*)carve((size_t)D_IN * D_HID * sizeof(unsigned short));
    unsigned short* W2T = (unsigned short*)carve((size_t)D_HID * D_IN * sizeof(unsigned short));
    unsigned int* t2b = xb;   // reuse: xb dead after gather1
    (void)ws_size;

    // 1. CSR build: bin (LDS-sorted, no deg atomics) -> scanB -> count -> place
    hipMemsetAsync(bcur, 0, 256 * sizeof(int), stream);
    bin_kernel<<<(N_EDGES + CHUNK - 1) / CHUNK, 256, 0, stream>>>(
        src, dst, bcur, binned, N_EDGES);
    scanB<<<1, 256, 0, stream>>>(bcur, brow);
    count_kernel<<<NBKT, 256, 0, stream>>>(binned, bcur, brow, deg, dinv,
                                           rowptr, N_NODES);
    place_kernel<<<NBKT, 256, 0, stream>>>(binned, bcur, rowptr, dinv,
                                           eS, eWt, N_NODES);

    // 2. conversions
    cvt_bf16<<<(N_NODES * D_IN / 4 + 255) / 256, 256, 0, stream>>>(
        (const float4*)x, (uint2*)xb, N_NODES * D_IN / 4);
    cvtT_both<<<(2 * D_IN * D_HID + 255) / 256, 256, 0, stream>>>(W1, W2, W1T, W2T);

    // 3. aggb = bf16(S @ x)
    gather_agg_bf16<true><<<(N_NODES + 3) / 4, 256, 0, stream>>>(
        xb, eS, eWt, rowptr, deg, dinv, nullptr, (void*)aggb, N_NODES);

    // 4. h1b = bf16(relu(aggb @ W1 + b1))   [MFMA]
    gemm_mfma<D_HID, D_IN, 1><<<(N_NODES + 127) / 128, 256, 0, stream>>>(
        W1T, aggb, b1, (unsigned short*)h1b, N_NODES);

    // 5. t2b = bf16(h1b @ W2)               [MFMA]
    gemm_mfma<D_IN, D_HID, 2><<<(N_NODES + 127) / 128, 256, 0, stream>>>(
        W2T, h1b, nullptr, (unsigned short*)t2b, N_NODES);

    // 6. out = S @ t2 + b2
    gather_agg_bf16<false><<<(N_NODES + 3) / 4, 256, 0, stream>>>(
        t2b, eS, eWt, rowptr, deg, dinv, b2, (void*)out, N_NODES);
}

// Round 9
// 293.853 us; speedup vs baseline: 1.3289x; 1.0602x over previous
//
#include <hip/hip_runtime.h>

#define N_NODES 50000
#define N_EDGES 1600000
#define D_IN 128
#define D_HID 256

#define NBKT 196          // buckets = dst >> 8
#define BCAP 12288        // per-bucket capacity (mean 8163, +45 sigma)
#define CHUNK 4096        // edges per bin-kernel block

typedef short bh8 __attribute__((ext_vector_type(8)));   // 8 bf16 (4 VGPRs)
typedef float f32x4 __attribute__((ext_vector_type(4))); // MFMA C/D

// ---------------------------------------------------------------------------
__device__ inline unsigned int f2_to_bf16x2(float a, float b) {
    unsigned int ua = __float_as_uint(a);
    ua = (ua + 0x7FFFu + ((ua >> 16) & 1u)) >> 16;
    unsigned int ub = __float_as_uint(b);
    ub = (ub + 0x7FFFu + ((ub >> 16) & 1u)) >> 16;
    return ua | (ub << 16);
}
__device__ inline unsigned short f_to_bf16(float a) {
    unsigned int ua = __float_as_uint(a);
    return (unsigned short)((ua + 0x7FFFu + ((ua >> 16) & 1u)) >> 16);
}
__device__ inline float2 bf16x2_to_f2(unsigned int p) {
    float2 r;
    r.x = __uint_as_float(p << 16);
    r.y = __uint_as_float(p & 0xFFFF0000u);
    return r;
}

// ---------------------------------------------------------------------------
// Phase A: coarse binning by dst>>8 with IN-LDS bucket sort so the global
// bucket-segment writes are contiguous (full-line merging). No deg atomics.
__global__ __launch_bounds__(256) void bin_kernel(
        const int* __restrict__ src, const int* __restrict__ dst,
        int* __restrict__ bcur, unsigned int* __restrict__ binned, int E) {
    __shared__ unsigned int staged[CHUNK];   // 16 KB
    __shared__ unsigned int sorted[CHUNK];   // 16 KB
    __shared__ int hist[NBKT], lbase[NBKT], gbase[NBKT];
    __shared__ int sc[256];
    const int tid = threadIdx.x;
    if (tid < NBKT) hist[tid] = 0;
    __syncthreads();
    const int cbase = blockIdx.x * CHUNK;
    const int n = min(CHUNK, E - cbase);
    for (int i = tid; i < n; i += 256) {
        int s = src[cbase + i], d = dst[cbase + i];
        staged[i] = ((unsigned)s << 16) | (unsigned)d;   // d < 50000 < 2^16
        atomicAdd(&hist[d >> 8], 1);
    }
    __syncthreads();
    // exclusive scan of hist[196] + one global reservation per bucket
    int h = (tid < NBKT) ? hist[tid] : 0;
    sc[tid] = h;
    __syncthreads();
    for (int off = 1; off < 256; off <<= 1) {
        int a = (tid >= off) ? sc[tid - off] : 0;
        __syncthreads();
        sc[tid] += a;
        __syncthreads();
    }
    if (tid < NBKT) {
        lbase[tid] = sc[tid] - h;
        gbase[tid] = h ? atomicAdd(&bcur[tid], h) : 0;
        hist[tid] = 0;                                   // reuse as cursor
    }
    __syncthreads();
    // permute into bucket order in LDS
    for (int i = tid; i < n; i += 256) {
        unsigned r = staged[i];
        int b = (r & 0xFFFF) >> 8;
        sorted[lbase[b] + atomicAdd(&hist[b], 1)] = r;
    }
    __syncthreads();
    // contiguous segment write-out: consecutive j -> consecutive addresses
    for (int j = tid; j < n; j += 256) {
        unsigned r = sorted[j];
        int b = (r & 0xFFFF) >> 8;
        binned[(size_t)b * BCAP + gbase[b] + (j - lbase[b])] = r;
    }
}

// ---------------------------------------------------------------------------
// Exclusive scan of the 196 bucket counts -> bucket region bases.
__global__ __launch_bounds__(256) void scanB(const int* __restrict__ bcur,
                                             int* __restrict__ brow) {
    __shared__ int sc[256];
    const int tid = threadIdx.x;
    int v = (tid < NBKT) ? bcur[tid] : 0;
    sc[tid] = v;
    __syncthreads();
    for (int off = 1; off < 256; off <<= 1) {
        int a = (tid >= off) ? sc[tid - off] : 0;
        __syncthreads();
        sc[tid] += a;
        __syncthreads();
    }
    if (tid < NBKT) brow[tid] = sc[tid] - v;
}

// ---------------------------------------------------------------------------
// Per-bucket node histogram -> deg, dinv, rowptr.
__global__ __launch_bounds__(256) void count_kernel(
        const unsigned int* __restrict__ binned, const int* __restrict__ bcur,
        const int* __restrict__ brow, int* __restrict__ deg,
        float* __restrict__ dinv, int* __restrict__ rowptr, int nNodes) {
    __shared__ int h[256], sc[256];
    const int b = blockIdx.x, tid = threadIdx.x;
    h[tid] = 0;
    __syncthreads();
    const int cnt = bcur[b];
    for (int j = tid; j < cnt; j += 256)
        atomicAdd(&h[binned[(size_t)b * BCAP + j] & 0xFF], 1);
    __syncthreads();
    int d0 = h[tid];
    sc[tid] = d0;
    __syncthreads();
    for (int off = 1; off < 256; off <<= 1) {
        int a = (tid >= off) ? sc[tid - off] : 0;
        __syncthreads();
        sc[tid] += a;
        __syncthreads();
    }
    int node = b * 256 + tid;
    if (node < nNodes) {
        deg[node] = d0;
        dinv[node] = rsqrtf((float)(d0 + 1));
        rowptr[node] = brow[b] + sc[tid] - d0;
    }
}

// ---------------------------------------------------------------------------
// Phase B: within-bucket placement. src u16 staged in LDS then burst-copied;
// weight eW = dinv[s]*dinv[d] written directly (bucket window is L2-local).
__global__ __launch_bounds__(256) void place_kernel(
        const unsigned int* __restrict__ binned, const int* __restrict__ bcur,
        const int* __restrict__ rowptr, const float* __restrict__ dinv,
        unsigned short* __restrict__ eS, float* __restrict__ eW, int nNodes) {
    __shared__ int cur[256];
    __shared__ float sdinv[256];
    __shared__ unsigned short recS[BCAP];
    const int b = blockIdx.x, tid = threadIdx.x;
    const int nbase = b * 256;
    const int regionBase = rowptr[nbase];        // nbase <= 49920 < nNodes
    int node = nbase + tid;
    cur[tid] = (node < nNodes) ? (rowptr[node] - regionBase) : 0;
    sdinv[tid] = (node < nNodes) ? dinv[node] : 0.0f;
    __syncthreads();
    int cnt = bcur[b];
    if (cnt <= BCAP) {
        for (int j = tid; j < cnt; j += 256) {
            unsigned r = binned[(size_t)b * BCAP + j];
            int dl = r & 0xFF;
            int s = r >> 16;
            int p = atomicAdd(&cur[dl], 1);
            recS[p] = (unsigned short)s;
            eW[regionBase + p] = dinv[s] * sdinv[dl];
        }
        __syncthreads();
        for (int j = tid; j < cnt; j += 256)
            eS[regionBase + j] = recS[j];
    } else {                                     // never taken (45-sigma guard)
        for (int j = tid; j < cnt; j += 256) {
            unsigned r = binned[(size_t)b * BCAP + j];
            int dl = r & 0xFF;
            int s = r >> 16;
            int p = atomicAdd(&cur[dl], 1);
            eS[regionBase + p] = (unsigned short)s;
            eW[regionBase + p] = dinv[s] * sdinv[dl];
        }
    }
}

// ---------------------------------------------------------------------------
// f32 -> packed bf16x2 (4 floats / thread)
__global__ __launch_bounds__(256) void cvt_bf16(const float4* __restrict__ in,
                                                uint2* __restrict__ out, int n4) {
    int i = blockIdx.x * blockDim.x + threadIdx.x;
    if (i < n4) {
        float4 v = in[i];
        out[i] = make_uint2(f2_to_bf16x2(v.x, v.y), f2_to_bf16x2(v.z, v.w));
    }
}

// Both weights: W[k][n] fp32 -> WT[n][k] bf16
__global__ __launch_bounds__(256) void cvtT_both(const float* __restrict__ W1,
                                                 const float* __restrict__ W2,
                                                 unsigned short* __restrict__ W1T,
                                                 unsigned short* __restrict__ W2T) {
    int t = blockIdx.x * blockDim.x + threadIdx.x;
    const int SZ = D_IN * D_HID;
    if (t < SZ) {
        int n = t / D_IN, k = t - n * D_IN;       // W1T[n][k], K=128, N=256
        W1T[t] = f_to_bf16(W1[(size_t)k * D_HID + n]);
    } else if (t < 2 * SZ) {
        int u = t - SZ;
        int n = u / D_HID, k = u - n * D_HID;     // W2T[n][k], K=256, N=128
        W2T[u] = f_to_bf16(W2[(size_t)k * D_IN + n]);
    }
}

// ---------------------------------------------------------------------------
// Gather aggregation, bf16 rows, fp32 accumulate. One 64-lane wave per node.
template<bool OUT_BF16>
__global__ __launch_bounds__(256) void gather_agg_bf16(
        const unsigned int* __restrict__ hb,   // [N, 64] packed bf16x2
        const unsigned short* __restrict__ eS,
        const float* __restrict__ eW,
        const int* __restrict__ rowptr, const int* __restrict__ deg,
        const float* __restrict__ dinv, const float* __restrict__ bias,
        void* __restrict__ out, int n) {
    int lane = threadIdx.x & 63;
    int node = blockIdx.x * 4 + (threadIdx.x >> 6);
    if (node >= n) return;
    int start = rowptr[node];
    int cnt = deg[node];
    float dn = dinv[node];
    float2 hv = bf16x2_to_f2(hb[(size_t)node * 64 + lane]);
    float2 acc = make_float2(dn * dn * hv.x, dn * dn * hv.y);
    for (int c0 = 0; c0 < cnt; c0 += 64) {
        int m = min(64, cnt - c0);
        int   es = (lane < m) ? (int)eS[start + c0 + lane] : 0;
        float ws = (lane < m) ? eW[start + c0 + lane] : 0.0f;  // 0 kills OOB
        int mr = (m + 7) & ~7;
        for (int j = 0; j < mr; j += 8) {
            float2 vv[8];
            float ww[8];
            #pragma unroll
            for (int k = 0; k < 8; ++k) {
                int sj = __shfl(es, j + k);
                ww[k] = __shfl(ws, j + k);
                vv[k] = bf16x2_to_f2(hb[(size_t)sj * 64 + lane]);
            }
            #pragma unroll
            for (int k = 0; k < 8; ++k) {
                acc.x += ww[k] * vv[k].x;
                acc.y += ww[k] * vv[k].y;
            }
        }
    }
    if (OUT_BF16) {
        ((unsigned int*)out)[(size_t)node * 64 + lane] = f2_to_bf16x2(acc.x, acc.y);
    } else {
        float2 b = ((const float2*)bias)[lane];
        acc.x += b.x;
        acc.y += b.y;
        ((float2*)((float*)out + (size_t)node * D_IN))[lane] = acc;
    }
}

// ---------------------------------------------------------------------------
// Weight-stationary MFMA GEMM, zero LDS. Each wave owns (128 M-rows) x
// (TPW 16-col n-tiles) and keeps its B-fragments in registers (loaded once
// from the L2-resident transposed weight). Streams A in 16-row groups:
// KSTEPS independent 16B loads -> KSTEPS*TPW MFMAs -> immediate store.
// MODE 1: fused bias+ReLU. MODE 2: plain.
template<int N, int K, int TPW, int MODE>
__global__ __launch_bounds__(256) void gemm_mfma_ws(
        const unsigned short* __restrict__ WT,  // [N][K] bf16
        const unsigned int* __restrict__ Ab,    // [M][K/2] packed bf16
        const float* __restrict__ bias,
        unsigned short* __restrict__ Cb,        // [M][N] bf16
        int M) {
    constexpr int KSTEPS = K / 32;
    constexpr int NTG = N / (16 * TPW);          // n-groups per M-block
    const int gw = (blockIdx.x * 256 + threadIdx.x) >> 6;
    const int lane = threadIdx.x & 63;
    const int mb = gw / NTG;
    const int ng = gw - mb * NTG;
    const int m_base = mb * 128;
    if (m_base >= M) return;
    const int rit = lane & 15;                   // row/col-in-tile
    const int kg = lane >> 4;                    // k-group 0..3

    // B-fragments: resident for the whole kernel
    bh8 b[TPW][KSTEPS];
    float bv[TPW];
    #pragma unroll
    for (int t = 0; t < TPW; ++t) {
        const int col = (ng * TPW + t) * 16 + rit;
        #pragma unroll
        for (int ks = 0; ks < KSTEPS; ++ks)
            b[t][ks] = *(const bh8*)(WT + (size_t)col * K + ks * 32 + kg * 8);
        bv[t] = (MODE == 1) ? bias[col] : 0.0f;
    }

    #pragma unroll
    for (int rg = 0; rg < 8; ++rg) {
        const int mr = min(m_base + rg * 16 + rit, M - 1);
        bh8 a[KSTEPS];
        #pragma unroll
        for (int ks = 0; ks < KSTEPS; ++ks)
            a[ks] = *(const bh8*)(Ab + (size_t)mr * (K / 2) + ks * 16 + kg * 4);
        f32x4 acc[TPW];
        #pragma unroll
        for (int t = 0; t < TPW; ++t) acc[t] = (f32x4){0.f, 0.f, 0.f, 0.f};
        #pragma unroll
        for (int ks = 0; ks < KSTEPS; ++ks)
            #pragma unroll
            for (int t = 0; t < TPW; ++t)
                acc[t] = __builtin_amdgcn_mfma_f32_16x16x32_bf16(
                    a[ks], b[t][ks], acc[t], 0, 0, 0);
        // epilogue: C/D layout col=lane&15, row=(lane>>4)*4+i  [m89]
        #pragma unroll
        for (int t = 0; t < TPW; ++t) {
            const int col = (ng * TPW + t) * 16 + rit;
            #pragma unroll
            for (int i = 0; i < 4; ++i) {
                const int m = m_base + rg * 16 + kg * 4 + i;
                float v = acc[t][i];
                if (MODE == 1) { v += bv[t]; v = fmaxf(v, 0.0f); }
                if (m < M) Cb[(size_t)m * N + col] = f_to_bf16(v);
            }
        }
    }
}

// ---------------------------------------------------------------------------
extern "C" void kernel_launch(void* const* d_in, const int* in_sizes, int n_in,
                              void* d_out, int out_size, void* d_ws, size_t ws_size,
                              hipStream_t stream) {
    const float* x  = (const float*)d_in[0];
    const int*   ei = (const int*)d_in[1];          // [2, E] int32
    const float* W1 = (const float*)d_in[2];
    const float* b1 = (const float*)d_in[3];
    const float* W2 = (const float*)d_in[4];
    const float* b2 = (const float*)d_in[5];
    const int* src = ei;
    const int* dst = ei + N_EDGES;
    float* out = (float*)d_out;

    char* ws = (char*)d_ws;
    size_t off = 0;
    auto carve = [&](size_t bytes) {
        char* p = ws + off;
        off += (bytes + 255) & ~size_t(255);
        return p;
    };
    int*   bcur      = (int*)  carve(256 * sizeof(int));
    int*   brow      = (int*)  carve(256 * sizeof(int));
    int*   deg       = (int*)  carve(N_NODES * sizeof(int));
    int*   rowptr    = (int*)  carve(N_NODES * sizeof(int));
    float* dinv      = (float*)carve(N_NODES * sizeof(float));
    unsigned int*   binned = (unsigned int*)  carve((size_t)NBKT * BCAP * sizeof(unsigned int));
    unsigned short* eS     = (unsigned short*)carve((size_t)N_EDGES * sizeof(unsigned short));
    float*          eWt    = (float*)         carve((size_t)N_EDGES * sizeof(float));
    unsigned int* xb   = (unsigned int*)carve((size_t)N_NODES * 64 * sizeof(unsigned int));
    unsigned int* aggb = (unsigned int*)carve((size_t)N_NODES * 64 * sizeof(unsigned int));
    unsigned int* h1b  = (unsigned int*)carve((size_t)N_NODES * 128 * sizeof(unsigned int));
    unsigned short* W1T = (unsigned short*)carve((size_t)D_IN * D_HID * sizeof(unsigned short));
    unsigned short* W2T = (unsigned short*)carve((size_t)D_HID * D_IN * sizeof(unsigned short));
    unsigned int* t2b = xb;   // reuse: xb dead after gather1
    (void)ws_size;

    // 1. CSR build: bin (LDS-sorted, no deg atomics) -> scanB -> count -> place
    hipMemsetAsync(bcur, 0, 256 * sizeof(int), stream);
    bin_kernel<<<(N_EDGES + CHUNK - 1) / CHUNK, 256, 0, stream>>>(
        src, dst, bcur, binned, N_EDGES);
    scanB<<<1, 256, 0, stream>>>(bcur, brow);
    count_kernel<<<NBKT, 256, 0, stream>>>(binned, bcur, brow, deg, dinv,
                                           rowptr, N_NODES);
    place_kernel<<<NBKT, 256, 0, stream>>>(binned, bcur, rowptr, dinv,
                                           eS, eWt, N_NODES);

    // 2. conversions
    cvt_bf16<<<(N_NODES * D_IN / 4 + 255) / 256, 256, 0, stream>>>(
        (const float4*)x, (uint2*)xb, N_NODES * D_IN / 4);
    cvtT_both<<<(2 * D_IN * D_HID + 255) / 256, 256, 0, stream>>>(W1, W2, W1T, W2T);

    // 3. aggb = bf16(S @ x)
    gather_agg_bf16<true><<<(N_NODES + 3) / 4, 256, 0, stream>>>(
        xb, eS, eWt, rowptr, deg, dinv, nullptr, (void*)aggb, N_NODES);

    const int mB = (N_NODES + 127) / 128;        // 391 M-blocks

    // 4. h1b = bf16(relu(aggb @ W1 + b1))   [MFMA, weight-stationary]
    {
        const int waves = mB * (D_HID / 32);     // TPW=2 -> 8 n-groups
        gemm_mfma_ws<D_HID, D_IN, 2, 1><<<(waves + 3) / 4, 256, 0, stream>>>(
            W1T, aggb, b1, (unsigned short*)h1b, N_NODES);
    }

    // 5. t2b = bf16(h1b @ W2)               [MFMA, weight-stationary]
    {
        const int waves = mB * (D_IN / 16);      // TPW=1 -> 8 n-groups
        gemm_mfma_ws<D_IN, D_HID, 1, 2><<<(waves + 3) / 4, 256, 0, stream>>>(
            W2T, h1b, nullptr, (unsigned short*)t2b, N_NODES);
    }

    // 6. out = S @ t2 + b2
    gather_agg_bf16<false><<<(N_NODES + 3) / 4, 256, 0, stream>>>(
        t2b, eS, eWt, rowptr, deg, dinv, b2, (void*)out, N_NODES);
}

// Round 10
// 293.787 us; speedup vs baseline: 1.3292x; 1.0002x over previous
//
#include <hip/hip_runtime.h>

#define N_NODES 50000
#define N_EDGES 1600000
#define D_IN 128
#define D_HID 256

#define NBKT 196          // buckets = dst >> 8
#define BCAP 12288        // per-bucket capacity (mean 8163, +45 sigma)
#define CHUNK 4096        // edges per bin-kernel block

typedef short bh8 __attribute__((ext_vector_type(8)));   // 8 bf16 (4 VGPRs)
typedef float f32x4 __attribute__((ext_vector_type(4))); // MFMA C/D

// ---------------------------------------------------------------------------
__device__ inline unsigned int f2_to_bf16x2(float a, float b) {
    unsigned int ua = __float_as_uint(a);
    ua = (ua + 0x7FFFu + ((ua >> 16) & 1u)) >> 16;
    unsigned int ub = __float_as_uint(b);
    ub = (ub + 0x7FFFu + ((ub >> 16) & 1u)) >> 16;
    return ua | (ub << 16);
}
__device__ inline unsigned short f_to_bf16(float a) {
    unsigned int ua = __float_as_uint(a);
    return (unsigned short)((ua + 0x7FFFu + ((ua >> 16) & 1u)) >> 16);
}
__device__ inline float2 bf16x2_to_f2(unsigned int p) {
    float2 r;
    r.x = __uint_as_float(p << 16);
    r.y = __uint_as_float(p & 0xFFFF0000u);
    return r;
}

// ---------------------------------------------------------------------------
// Phase A: coarse binning by dst>>8 with IN-LDS bucket sort so the global
// bucket-segment writes are contiguous (full-line merging). No deg atomics.
__global__ __launch_bounds__(256) void bin_kernel(
        const int* __restrict__ src, const int* __restrict__ dst,
        int* __restrict__ bcur, unsigned int* __restrict__ binned, int E) {
    __shared__ unsigned int staged[CHUNK];   // 16 KB
    __shared__ unsigned int sorted[CHUNK];   // 16 KB
    __shared__ int hist[NBKT], lbase[NBKT], gbase[NBKT];
    __shared__ int sc[256];
    const int tid = threadIdx.x;
    if (tid < NBKT) hist[tid] = 0;
    __syncthreads();
    const int cbase = blockIdx.x * CHUNK;
    const int n = min(CHUNK, E - cbase);
    for (int i = tid; i < n; i += 256) {
        int s = src[cbase + i], d = dst[cbase + i];
        staged[i] = ((unsigned)s << 16) | (unsigned)d;   // d < 50000 < 2^16
        atomicAdd(&hist[d >> 8], 1);
    }
    __syncthreads();
    // exclusive scan of hist[196] + one global reservation per bucket
    int h = (tid < NBKT) ? hist[tid] : 0;
    sc[tid] = h;
    __syncthreads();
    for (int off = 1; off < 256; off <<= 1) {
        int a = (tid >= off) ? sc[tid - off] : 0;
        __syncthreads();
        sc[tid] += a;
        __syncthreads();
    }
    if (tid < NBKT) {
        lbase[tid] = sc[tid] - h;
        gbase[tid] = h ? atomicAdd(&bcur[tid], h) : 0;
        hist[tid] = 0;                                   // reuse as cursor
    }
    __syncthreads();
    // permute into bucket order in LDS
    for (int i = tid; i < n; i += 256) {
        unsigned r = staged[i];
        int b = (r & 0xFFFF) >> 8;
        sorted[lbase[b] + atomicAdd(&hist[b], 1)] = r;
    }
    __syncthreads();
    // contiguous segment write-out: consecutive j -> consecutive addresses
    for (int j = tid; j < n; j += 256) {
        unsigned r = sorted[j];
        int b = (r & 0xFFFF) >> 8;
        binned[(size_t)b * BCAP + gbase[b] + (j - lbase[b])] = r;
    }
}

// ---------------------------------------------------------------------------
// Exclusive scan of the 196 bucket counts -> bucket region bases.
__global__ __launch_bounds__(256) void scanB(const int* __restrict__ bcur,
                                             int* __restrict__ brow) {
    __shared__ int sc[256];
    const int tid = threadIdx.x;
    int v = (tid < NBKT) ? bcur[tid] : 0;
    sc[tid] = v;
    __syncthreads();
    for (int off = 1; off < 256; off <<= 1) {
        int a = (tid >= off) ? sc[tid - off] : 0;
        __syncthreads();
        sc[tid] += a;
        __syncthreads();
    }
    if (tid < NBKT) brow[tid] = sc[tid] - v;
}

// ---------------------------------------------------------------------------
// Per-bucket node histogram -> deg, dinv, rowptr.
__global__ __launch_bounds__(256) void count_kernel(
        const unsigned int* __restrict__ binned, const int* __restrict__ bcur,
        const int* __restrict__ brow, int* __restrict__ deg,
        float* __restrict__ dinv, int* __restrict__ rowptr, int nNodes) {
    __shared__ int h[256], sc[256];
    const int b = blockIdx.x, tid = threadIdx.x;
    h[tid] = 0;
    __syncthreads();
    const int cnt = bcur[b];
    for (int j = tid; j < cnt; j += 256)
        atomicAdd(&h[binned[(size_t)b * BCAP + j] & 0xFF], 1);
    __syncthreads();
    int d0 = h[tid];
    sc[tid] = d0;
    __syncthreads();
    for (int off = 1; off < 256; off <<= 1) {
        int a = (tid >= off) ? sc[tid - off] : 0;
        __syncthreads();
        sc[tid] += a;
        __syncthreads();
    }
    int node = b * 256 + tid;
    if (node < nNodes) {
        deg[node] = d0;
        dinv[node] = rsqrtf((float)(d0 + 1));
        rowptr[node] = brow[b] + sc[tid] - d0;
    }
}

// ---------------------------------------------------------------------------
// Phase B: within-bucket placement. src u16 staged in LDS then burst-copied;
// weight eW = dinv[s]*dinv[d] written directly (bucket window is L2-local).
__global__ __launch_bounds__(256) void place_kernel(
        const unsigned int* __restrict__ binned, const int* __restrict__ bcur,
        const int* __restrict__ rowptr, const float* __restrict__ dinv,
        unsigned short* __restrict__ eS, float* __restrict__ eW, int nNodes) {
    __shared__ int cur[256];
    __shared__ float sdinv[256];
    __shared__ unsigned short recS[BCAP];
    const int b = blockIdx.x, tid = threadIdx.x;
    const int nbase = b * 256;
    const int regionBase = rowptr[nbase];        // nbase <= 49920 < nNodes
    int node = nbase + tid;
    cur[tid] = (node < nNodes) ? (rowptr[node] - regionBase) : 0;
    sdinv[tid] = (node < nNodes) ? dinv[node] : 0.0f;
    __syncthreads();
    int cnt = bcur[b];
    if (cnt <= BCAP) {
        for (int j = tid; j < cnt; j += 256) {
            unsigned r = binned[(size_t)b * BCAP + j];
            int dl = r & 0xFF;
            int s = r >> 16;
            int p = atomicAdd(&cur[dl], 1);
            recS[p] = (unsigned short)s;
            eW[regionBase + p] = dinv[s] * sdinv[dl];
        }
        __syncthreads();
        for (int j = tid; j < cnt; j += 256)
            eS[regionBase + j] = recS[j];
    } else {                                     // never taken (45-sigma guard)
        for (int j = tid; j < cnt; j += 256) {
            unsigned r = binned[(size_t)b * BCAP + j];
            int dl = r & 0xFF;
            int s = r >> 16;
            int p = atomicAdd(&cur[dl], 1);
            eS[regionBase + p] = (unsigned short)s;
            eW[regionBase + p] = dinv[s] * sdinv[dl];
        }
    }
}

// ---------------------------------------------------------------------------
// f32 -> packed bf16x2 (4 floats / thread)
__global__ __launch_bounds__(256) void cvt_bf16(const float4* __restrict__ in,
                                                uint2* __restrict__ out, int n4) {
    int i = blockIdx.x * blockDim.x + threadIdx.x;
    if (i < n4) {
        float4 v = in[i];
        out[i] = make_uint2(f2_to_bf16x2(v.x, v.y), f2_to_bf16x2(v.z, v.w));
    }
}

// Both weights: W[k][n] fp32 -> WT[n][k] bf16
__global__ __launch_bounds__(256) void cvtT_both(const float* __restrict__ W1,
                                                 const float* __restrict__ W2,
                                                 unsigned short* __restrict__ W1T,
                                                 unsigned short* __restrict__ W2T) {
    int t = blockIdx.x * blockDim.x + threadIdx.x;
    const int SZ = D_IN * D_HID;
    if (t < SZ) {
        int n = t / D_IN, k = t - n * D_IN;       // W1T[n][k], K=128, N=256
        W1T[t] = f_to_bf16(W1[(size_t)k * D_HID + n]);
    } else if (t < 2 * SZ) {
        int u = t - SZ;
        int n = u / D_HID, k = u - n * D_HID;     // W2T[n][k], K=256, N=128
        W2T[u] = f_to_bf16(W2[(size_t)k * D_IN + n]);
    }
}

// ---------------------------------------------------------------------------
// Gather aggregation, bf16 rows, fp32 accumulate. One 64-lane wave per node;
// 32 lanes cover a row (uint2 = 8B/lane), TWO edges in flight per step:
// lo half-wave takes even edges, hi half odd edges. Cross-half reduce at end.
template<bool OUT_BF16>
__global__ __launch_bounds__(256) void gather_agg_bf16(
        const uint2* __restrict__ hb2,   // [N][32] packed bf16x4 (= [N,128]bf16)
        const unsigned short* __restrict__ eS,
        const float* __restrict__ eW,
        const int* __restrict__ rowptr, const int* __restrict__ deg,
        const float* __restrict__ dinv, const float* __restrict__ bias,
        void* __restrict__ out, int n) {
    const int lane = threadIdx.x & 63;
    const int node = blockIdx.x * 4 + (threadIdx.x >> 6);
    if (node >= n) return;
    const int hl = lane & 31;
    const int odd = (lane >> 5) & 1;             // 0 = even edges, 1 = odd
    const int start = rowptr[node];
    const int cnt = deg[node];
    const float dn = dinv[node];

    float4 acc = make_float4(0.f, 0.f, 0.f, 0.f);
    // self-loop term: lo half only
    if (!odd) {
        uint2 hv = hb2[(size_t)node * 32 + hl];
        float2 a = bf16x2_to_f2(hv.x), b = bf16x2_to_f2(hv.y);
        float w = dn * dn;
        acc.x = w * a.x; acc.y = w * a.y; acc.z = w * b.x; acc.w = w * b.y;
    }

    for (int c0 = 0; c0 < cnt; c0 += 64) {
        int m = min(64, cnt - c0);
        int   es = (lane < m) ? (int)eS[start + c0 + lane] : 0;
        float ws = (lane < m) ? eW[start + c0 + lane] : 0.0f;  // 0 kills OOB
        int steps = (m + 1) >> 1;                 // pairs
        int sr = (steps + 3) & ~3;
        for (int j = 0; j < sr; j += 4) {
            uint2 vv[4];
            float ww[4];
            #pragma unroll
            for (int k = 0; k < 4; ++k) {
                int idx = ((j + k) << 1) | odd;   // my half's edge slot
                int sj = __shfl(es, idx);
                ww[k] = __shfl(ws, idx);
                vv[k] = hb2[(size_t)sj * 32 + hl];
            }
            #pragma unroll
            for (int k = 0; k < 4; ++k) {
                float2 a = bf16x2_to_f2(vv[k].x), b = bf16x2_to_f2(vv[k].y);
                acc.x += ww[k] * a.x;
                acc.y += ww[k] * a.y;
                acc.z += ww[k] * b.x;
                acc.w += ww[k] * b.y;
            }
        }
    }

    // combine halves (both halves computed partials for the same elements)
    acc.x += __shfl_xor(acc.x, 32);
    acc.y += __shfl_xor(acc.y, 32);
    acc.z += __shfl_xor(acc.z, 32);
    acc.w += __shfl_xor(acc.w, 32);

    if (lane < 32) {
        if (OUT_BF16) {
            ((uint2*)out)[(size_t)node * 32 + hl] =
                make_uint2(f2_to_bf16x2(acc.x, acc.y), f2_to_bf16x2(acc.z, acc.w));
        } else {
            float4 b = ((const float4*)bias)[hl];
            acc.x += b.x; acc.y += b.y; acc.z += b.z; acc.w += b.w;
            ((float4*)((float*)out + (size_t)node * D_IN))[hl] = acc;
        }
    }
}

// ---------------------------------------------------------------------------
// Weight-stationary MFMA GEMM, zero LDS. Each wave owns (128 M-rows) x
// (TPW 16-col n-tiles) and keeps its B-fragments in registers.
// MODE 1: fused bias+ReLU. MODE 2: plain.
template<int N, int K, int TPW, int MODE>
__global__ __launch_bounds__(256) void gemm_mfma_ws(
        const unsigned short* __restrict__ WT,  // [N][K] bf16
        const unsigned int* __restrict__ Ab,    // [M][K/2] packed bf16
        const float* __restrict__ bias,
        unsigned short* __restrict__ Cb,        // [M][N] bf16
        int M) {
    constexpr int KSTEPS = K / 32;
    constexpr int NTG = N / (16 * TPW);          // n-groups per M-block
    const int gw = (blockIdx.x * 256 + threadIdx.x) >> 6;
    const int lane = threadIdx.x & 63;
    const int mb = gw / NTG;
    const int ng = gw - mb * NTG;
    const int m_base = mb * 128;
    if (m_base >= M) return;
    const int rit = lane & 15;                   // row/col-in-tile
    const int kg = lane >> 4;                    // k-group 0..3

    bh8 b[TPW][KSTEPS];
    float bv[TPW];
    #pragma unroll
    for (int t = 0; t < TPW; ++t) {
        const int col = (ng * TPW + t) * 16 + rit;
        #pragma unroll
        for (int ks = 0; ks < KSTEPS; ++ks)
            b[t][ks] = *(const bh8*)(WT + (size_t)col * K + ks * 32 + kg * 8);
        bv[t] = (MODE == 1) ? bias[col] : 0.0f;
    }

    #pragma unroll
    for (int rg = 0; rg < 8; ++rg) {
        const int mr = min(m_base + rg * 16 + rit, M - 1);
        bh8 a[KSTEPS];
        #pragma unroll
        for (int ks = 0; ks < KSTEPS; ++ks)
            a[ks] = *(const bh8*)(Ab + (size_t)mr * (K / 2) + ks * 16 + kg * 4);
        f32x4 acc[TPW];
        #pragma unroll
        for (int t = 0; t < TPW; ++t) acc[t] = (f32x4){0.f, 0.f, 0.f, 0.f};
        #pragma unroll
        for (int ks = 0; ks < KSTEPS; ++ks)
            #pragma unroll
            for (int t = 0; t < TPW; ++t)
                acc[t] = __builtin_amdgcn_mfma_f32_16x16x32_bf16(
                    a[ks], b[t][ks], acc[t], 0, 0, 0);
        // epilogue: C/D layout col=lane&15, row=(lane>>4)*4+i  [m89]
        #pragma unroll
        for (int t = 0; t < TPW; ++t) {
            const int col = (ng * TPW + t) * 16 + rit;
            #pragma unroll
            for (int i = 0; i < 4; ++i) {
                const int m = m_base + rg * 16 + kg * 4 + i;
                float v = acc[t][i];
                if (MODE == 1) { v += bv[t]; v = fmaxf(v, 0.0f); }
                if (m < M) Cb[(size_t)m * N + col] = f_to_bf16(v);
            }
        }
    }
}

// ---------------------------------------------------------------------------
extern "C" void kernel_launch(void* const* d_in, const int* in_sizes, int n_in,
                              void* d_out, int out_size, void* d_ws, size_t ws_size,
                              hipStream_t stream) {
    const float* x  = (const float*)d_in[0];
    const int*   ei = (const int*)d_in[1];          // [2, E] int32
    const float* W1 = (const float*)d_in[2];
    const float* b1 = (const float*)d_in[3];
    const float* W2 = (const float*)d_in[4];
    const float* b2 = (const float*)d_in[5];
    const int* src = ei;
    const int* dst = ei + N_EDGES;
    float* out = (float*)d_out;

    char* ws = (char*)d_ws;
    size_t off = 0;
    auto carve = [&](size_t bytes) {
        char* p = ws + off;
        off += (bytes + 255) & ~size_t(255);
        return p;
    };
    int*   bcur      = (int*)  carve(256 * sizeof(int));
    int*   brow      = (int*)  carve(256 * sizeof(int));
    int*   deg       = (int*)  carve(N_NODES * sizeof(int));
    int*   rowptr    = (int*)  carve(N_NODES * sizeof(int));
    float* dinv      = (float*)carve(N_NODES * sizeof(float));
    unsigned int*   binned = (unsigned int*)  carve((size_t)NBKT * BCAP * sizeof(unsigned int));
    unsigned short* eS     = (unsigned short*)carve((size_t)N_EDGES * sizeof(unsigned short));
    float*          eWt    = (float*)         carve((size_t)N_EDGES * sizeof(float));
    unsigned int* xb   = (unsigned int*)carve((size_t)N_NODES * 64 * sizeof(unsigned int));
    unsigned int* aggb = (unsigned int*)carve((size_t)N_NODES * 64 * sizeof(unsigned int));
    unsigned int* h1b  = (unsigned int*)carve((size_t)N_NODES * 128 * sizeof(unsigned int));
    unsigned short* W1T = (unsigned short*)carve((size_t)D_IN * D_HID * sizeof(unsigned short));
    unsigned short* W2T = (unsigned short*)carve((size_t)D_HID * D_IN * sizeof(unsigned short));
    unsigned int* t2b = xb;   // reuse: xb dead after gather1
    (void)ws_size;

    // 1. CSR build: bin (LDS-sorted, no deg atomics) -> scanB -> count -> place
    hipMemsetAsync(bcur, 0, 256 * sizeof(int), stream);
    bin_kernel<<<(N_EDGES + CHUNK - 1) / CHUNK, 256, 0, stream>>>(
        src, dst, bcur, binned, N_EDGES);
    scanB<<<1, 256, 0, stream>>>(bcur, brow);
    count_kernel<<<NBKT, 256, 0, stream>>>(binned, bcur, brow, deg, dinv,
                                           rowptr, N_NODES);
    place_kernel<<<NBKT, 256, 0, stream>>>(binned, bcur, rowptr, dinv,
                                           eS, eWt, N_NODES);

    // 2. conversions
    cvt_bf16<<<(N_NODES * D_IN / 4 + 255) / 256, 256, 0, stream>>>(
        (const float4*)x, (uint2*)xb, N_NODES * D_IN / 4);
    cvtT_both<<<(2 * D_IN * D_HID + 255) / 256, 256, 0, stream>>>(W1, W2, W1T, W2T);

    // 3. aggb = bf16(S @ x)
    gather_agg_bf16<true><<<(N_NODES + 3) / 4, 256, 0, stream>>>(
        (const uint2*)xb, eS, eWt, rowptr, deg, dinv, nullptr, (void*)aggb, N_NODES);

    const int mB = (N_NODES + 127) / 128;        // 391 M-blocks

    // 4. h1b = bf16(relu(aggb @ W1 + b1))   [MFMA, weight-stationary]
    {
        const int waves = mB * (D_HID / 32);     // TPW=2 -> 8 n-groups
        gemm_mfma_ws<D_HID, D_IN, 2, 1><<<(waves + 3) / 4, 256, 0, stream>>>(
            W1T, aggb, b1, (unsigned short*)h1b, N_NODES);
    }

    // 5. t2b = bf16(h1b @ W2)               [MFMA, weight-stationary]
    {
        const int waves = mB * (D_IN / 16);      // TPW=1 -> 8 n-groups
        gemm_mfma_ws<D_IN, D_HID, 1, 2><<<(waves + 3) / 4, 256, 0, stream>>>(
            W2T, h1b, nullptr, (unsigned short*)t2b, N_NODES);
    }

    // 6. out = S @ t2 + b2
    gather_agg_bf16<false><<<(N_NODES + 3) / 4, 256, 0, stream>>>(
        (const uint2*)t2b, eS, eWt, rowptr, deg, dinv, b2, (void*)out, N_NODES);
}